// Round 11
// baseline (112.888 us; speedup 1.0000x reference)
//
#include <hip/hip_runtime.h>

#define B_N 8
#define A_N 100000
#define M_N 64
#define TPB 256
#define PAIRS (A_N / 2)                               // 50000, A_N even
#define GX ((PAIRS + TPB - 1) / TPB)                  // 196 blocks per batch
#define NBLK (GX * B_N)                               // 1568

#define NBINS 256
#define BINW  12.0f         // covers a0 in [0, 3072); a0 <= 3000
#define MAXAW 50.0f
#define MARG  1.0f

// d_ws layout:
//   table  : u64 [B_N][NBINS]  (16 KB)  bin -> candidate-annotation bitmask
//   ann_t  : float4[B_N][M_N]  (8 KB)   {x1, x2, len, 0}
//   ws_num : float[B_N], ws_cnt : float[B_N], ticket : uint
// prep zeroes ws_num/ws_cnt/ticket each call (harness poisons ws to 0xAA).

__global__ __launch_bounds__(TPB) void rl_prep(
    const float* __restrict__ annotations,       // (B, M, 3)
    unsigned long long* __restrict__ table,
    float4* __restrict__ ann_t,
    float* __restrict__ ws_num, float* __restrict__ ws_cnt,
    unsigned int* __restrict__ ticket)
{
    const int b   = blockIdx.x;                  // 8 blocks, 1 per batch
    const int bin = threadIdx.x;                 // 256 bins
    const float binlo = bin * BINW;
    const float binhi = binlo + BINW;

    const float* p = annotations + b * M_N * 3;  // wave-uniform loads
    unsigned long long mask = 0ull;
    #pragma unroll 8
    for (int m = 0; m < M_N; ++m) {
        const float x1 = p[3 * m + 0], x2 = p[3 * m + 1], lab = p[3 * m + 2];
        if (lab != -1.0f) {
            // iou>=0.5 => overlap >= len/3 => a0 in [x1+len/3-aw, x2-len/3],
            // aw<=50. Margin 1.0 >> any fp32 rounding at coords <= ~3e3.
            const float len3 = (x2 - x1) * (1.0f / 3.0f);
            const float lo = x1 + len3 - MAXAW - MARG;
            const float hi = x2 - len3 + MARG;
            if (binlo <= hi && binhi > lo) mask |= (1ull << m);
        }
    }
    table[b * NBINS + bin] = mask;

    if (threadIdx.x < M_N) {
        const int m = threadIdx.x;
        float x1 = p[3 * m + 0], x2 = p[3 * m + 1], lab = p[3 * m + 2];
        if (lab == -1.0f) { x1 = 1e30f; x2 = 1e30f; }   // never in masks anyway
        ann_t[b * M_N + m] = make_float4(x1, x2, x2 - x1, 0.0f);
    }
    // zero the cross-kernel accumulators (poisoned 0xAA by harness)
    if (threadIdx.x == 64) { ws_num[b] = 0.0f; ws_cnt[b] = 0.0f; }
    if (b == 0 && threadIdx.x == 65) *ticket = 0u;
}

__global__ __launch_bounds__(TPB) void rl_main(
    const float* __restrict__ regressions,   // (B, A, 2)
    const float* __restrict__ anchors,       // (1, A, 2)
    const unsigned long long* __restrict__ table,
    const float4* __restrict__ ann_t,
    float* __restrict__ ws_num, float* __restrict__ ws_cnt,
    unsigned int* __restrict__ ticket,
    float* __restrict__ out)
{
    const int b = blockIdx.y;
    const int tid = threadIdx.x;

    // One float4 = two adjacent anchors per thread; direct L2 gathers.
    const int pair_raw = blockIdx.x * TPB + tid;
    const bool pact = (pair_raw < PAIRS);
    const int pair = pact ? pair_raw : (PAIRS - 1);
    const float4 anc2 = ((const float4*)anchors)[pair];

    const unsigned long long* tb = table + b * NBINS;
    const float4* annb = ann_t + b * M_N;

    float lsum = 0.0f, lpos = 0.0f;
    #pragma unroll
    for (int k = 0; k < 2; ++k) {
        const float a0 = k ? anc2.z : anc2.x;
        const float a1 = k ? anc2.w : anc2.y;
        const float aw = a1 - a0;
        const int a_idx = 2 * pair + k;

        const int bin = min(max((int)(a0 * (1.0f / BINW)), 0), NBINS - 1);
        unsigned long long mask = tb[bin];

        // exact argmax over the candidate superset, ascending index,
        // strict '>' (division-free cross-mul on iou = iw/(S-iw), S=aw+len)
        float iwb = -1.0f, Sb = 1.0f;    // encodes iou = -1
        int idx = 0;
        while (mask) {
            const int m = __ffsll(mask) - 1;
            mask &= mask - 1;
            const float4 g = annb[m];
            const float iw = fmaxf(fminf(a1, g.y) - fmaxf(a0, g.x), 0.0f);
            const float S  = aw + g.z;
            if (iw * Sb > iwb * S) { iwb = iw; Sb = S; idx = m; }
        }

        // exact gate, reference rounding order: ua = (aw+len) - iw
        const float ua  = fmaxf(Sb - iwb, 1e-8f);
        const float iou = iwb / ua;
        if (pact && iou >= 0.5f) {
            const float4 g = annb[idx];
            const float gw0 = g.z;
            const float gcx = g.x + 0.5f * gw0;
            const float gw  = fmaxf(gw0, 1.0f);
            const float acx = a0 + 0.5f * aw;
            const float tdx = ((gcx - acx) / aw) / 0.1f;
            const float tdw = logf(gw / aw) / 0.2f;
            const float2 rg =
                ((const float2*)regressions)[(size_t)b * A_N + a_idx];
            const float d0 = fabsf(tdx - rg.x);
            const float d1 = fabsf(tdw - rg.y);
            const float inv9 = 1.0f / 9.0f;
            const float s0 = (d0 <= inv9) ? 4.5f * d0 * d0 : d0 - 0.5f / 9.0f;
            const float s1 = (d1 <= inv9) ? 4.5f * d1 * d1 : d1 - 0.5f / 9.0f;
            lsum += s0 + s1;
            lpos += 1.0f;
        }
    }

    for (int o = 32; o > 0; o >>= 1) {
        lsum += __shfl_down(lsum, o, 64);
        lpos += __shfl_down(lpos, o, 64);
    }
    __shared__ float wsum[TPB / 64], wpos[TPB / 64];
    __shared__ int winner;
    const int wid  = tid >> 6;
    const int lane = tid & 63;
    if (lane == 0) { wsum[wid] = lsum; wpos[wid] = lpos; }
    __syncthreads();

    if (tid == 0) {
        float s = 0.0f, p = 0.0f;
        #pragma unroll
        for (int w = 0; w < TPB / 64; ++w) { s += wsum[w]; p += wpos[w]; }
        // relaxed device-coherent accumulation (no per-block cache fences)
        const float r1 = __hip_atomic_fetch_add(&ws_num[b], s,
                             __ATOMIC_RELAXED, __HIP_MEMORY_SCOPE_AGENT);
        const float r2 = __hip_atomic_fetch_add(&ws_cnt[b], p,
                             __ATOMIC_RELAXED, __HIP_MEMORY_SCOPE_AGENT);
        // consume results: forces s_waitcnt on both RMWs BEFORE the ticket
        // increment issues -> our adds are globally applied first.
        asm volatile("" :: "v"(r1), "v"(r2));
        const unsigned int old = __hip_atomic_fetch_add(
            ticket, 1u, __ATOMIC_RELAXED, __HIP_MEMORY_SCOPE_AGENT);
        winner = (old == NBLK - 1) ? 1 : 0;
    }
    __syncthreads();

    if (winner && tid == 0) {
        // last block: every other block's RMWs are already at the coherent
        // point (their ticket increments followed their adds). Read back
        // with coherent atomic loads and finish.
        float acc = 0.0f;
        #pragma unroll
        for (int i = 0; i < B_N; ++i) {
            const float sn = __hip_atomic_load(&ws_num[i],
                                 __ATOMIC_RELAXED, __HIP_MEMORY_SCOPE_AGENT);
            const float sc = __hip_atomic_load(&ws_cnt[i],
                                 __ATOMIC_RELAXED, __HIP_MEMORY_SCOPE_AGENT);
            const float cnt = 2.0f * sc;
            acc += (cnt > 0.0f) ? sn / fmaxf(cnt, 1.0f) : 0.0f;
        }
        out[0] = acc * (1.0f / (float)B_N);
    }
}

extern "C" void kernel_launch(void* const* d_in, const int* in_sizes, int n_in,
                              void* d_out, int out_size, void* d_ws, size_t ws_size,
                              hipStream_t stream) {
    const float* regressions = (const float*)d_in[0];
    const float* anchors     = (const float*)d_in[1];
    const float* annotations = (const float*)d_in[2];
    float* out = (float*)d_out;

    unsigned long long* table = (unsigned long long*)d_ws;      // [B_N*NBINS]
    float4* ann_t  = (float4*)(table + B_N * NBINS);            // [B_N*M_N]
    float*  ws_num = (float*)(ann_t + B_N * M_N);               // [B_N]
    float*  ws_cnt = ws_num + B_N;                              // [B_N]
    unsigned int* ticket = (unsigned int*)(ws_cnt + B_N);

    rl_prep<<<B_N, TPB, 0, stream>>>(annotations, table, ann_t,
                                     ws_num, ws_cnt, ticket);
    rl_main<<<dim3(GX, B_N), TPB, 0, stream>>>(regressions, anchors, table,
                                               ann_t, ws_num, ws_cnt,
                                               ticket, out);
}

// Round 12
// 80.469 us; speedup vs baseline: 1.4029x; 1.4029x over previous
//
#include <hip/hip_runtime.h>

#define B_N 8
#define A_N 100000
#define M_N 64
#define TPB 256
#define PAIRS (A_N / 2)                               // 50000, A_N even
#define GX ((PAIRS + TPB - 1) / TPB)                  // 196 blocks per batch

#define NBINS 256
#define BINW  12.0f         // covers a0 in [0, 3072); a0 <= 3000
#define MAXAW 50.0f
#define MARG  1.0f

// d_ws layout:
//   recs  : float4[B_N*NBINS*4]  (128 KB)  64-B per-bin record:
//           r0 = {bits(mask_rest_lo), bits(mask_rest_hi), 0, 0}
//           r1..r3 = first three candidates {x1, x2, len, 0}
//                    (sentinel {1e30,1e30,0,0} in unused slots)
//   ann_t : float4[B_N*M_N]      (8 KB)   fallback for mask_rest bits
//   ws_num: float[B_N*GX], ws_cnt: float[B_N*GX]
// Every slot is rewritten each call before being read (poison-proof).

__global__ __launch_bounds__(TPB) void rl_prep(
    const float* __restrict__ annotations,       // (B, M, 3)
    float4* __restrict__ recs,
    float4* __restrict__ ann_t)
{
    const int b   = blockIdx.x;                  // 8 blocks, 1 per batch
    const int bin = threadIdx.x;                 // 256 bins
    const float binlo = bin * BINW;
    const float binhi = binlo + BINW;

    const float* p = annotations + b * M_N * 3;  // wave-uniform loads
    const float4 sent = make_float4(1e30f, 1e30f, 0.0f, 0.0f);
    float4 c0 = sent, c1 = sent, c2 = sent;
    int cnt = 0;
    unsigned long long mrest = 0ull;
    for (int m = 0; m < M_N; ++m) {
        const float x1 = p[3 * m + 0], x2 = p[3 * m + 1], lab = p[3 * m + 2];
        if (lab != -1.0f) {
            // iou>=0.5 => overlap >= len/3 => a0 in [x1+len/3-aw, x2-len/3],
            // aw<=50. Margin 1.0 >> any fp32 rounding at coords <= ~3e3.
            const float len3 = (x2 - x1) * (1.0f / 3.0f);
            const float lo = x1 + len3 - MAXAW - MARG;
            const float hi = x2 - len3 + MARG;
            if (binlo <= hi && binhi > lo) {
                const float4 v = make_float4(x1, x2, x2 - x1, 0.0f);
                if      (cnt == 0) c0 = v;
                else if (cnt == 1) c1 = v;
                else if (cnt == 2) c2 = v;
                else               mrest |= (1ull << m);   // ascending > c2's m
                ++cnt;
            }
        }
    }
    float4* r = recs + (size_t)(b * NBINS + bin) * 4;
    r[0] = make_float4(__uint_as_float((unsigned int)(mrest & 0xffffffffull)),
                       __uint_as_float((unsigned int)(mrest >> 32)),
                       0.0f, 0.0f);
    r[1] = c0; r[2] = c1; r[3] = c2;

    if (threadIdx.x < M_N) {
        const int m = threadIdx.x;
        float x1 = p[3 * m + 0], x2 = p[3 * m + 1], lab = p[3 * m + 2];
        if (lab == -1.0f) { x1 = 1e30f; x2 = 1e30f; }   // never in masks anyway
        ann_t[b * M_N + m] = make_float4(x1, x2, x2 - x1, 0.0f);
    }
}

__global__ __launch_bounds__(TPB) void rl_main(
    const float* __restrict__ regressions,   // (B, A, 2)
    const float* __restrict__ anchors,       // (1, A, 2)
    const float4* __restrict__ recs,
    const float4* __restrict__ ann_t,
    float* __restrict__ ws_num, float* __restrict__ ws_cnt)
{
    const int b = blockIdx.y;
    const int tid = threadIdx.x;

    // One float4 = two adjacent anchors per thread; per anchor ONE 64-B
    // record (4 parallel same-line loads) carries everything: 2-deep
    // memory chain (anchor -> record), winner carries its values so the
    // epilogue needs no further gather. Sentinel candidates (iw clamps
    // to 0, S = aw) can "win" only when nothing real overlaps, and then
    // iou = 0 < 0.5 -> zero contribution, same as reference.
    const int pair_raw = blockIdx.x * TPB + tid;
    const bool pact = (pair_raw < PAIRS);
    const int pair = pact ? pair_raw : (PAIRS - 1);
    const float4 anc2 = ((const float4*)anchors)[pair];

    const float4* recb = recs + (size_t)b * NBINS * 4;
    const float4* annb = ann_t + b * M_N;

    float lsum = 0.0f, lpos = 0.0f;
    #pragma unroll
    for (int k = 0; k < 2; ++k) {
        const float a0 = k ? anc2.z : anc2.x;
        const float a1 = k ? anc2.w : anc2.y;
        const float aw = a1 - a0;
        const int a_idx = 2 * pair + k;

        const int bin = min(max((int)(a0 * (1.0f / BINW)), 0), NBINS - 1);
        const float4 r0 = recb[bin * 4 + 0];
        const float4 c0 = recb[bin * 4 + 1];
        const float4 c1 = recb[bin * 4 + 2];
        const float4 c2 = recb[bin * 4 + 3];

        // argmax over candidate superset, ascending index, strict '>'
        // (division-free cross-mul on iou = iw/(S-iw), S = aw+len)
        float iwb = -1.0f, Sb = 1.0f;    // encodes iou = -1
        float bx1 = 1e30f, blen = 0.0f;  // winner's values
        {
            const float iw = fmaxf(fminf(a1, c0.y) - fmaxf(a0, c0.x), 0.0f);
            const float S  = aw + c0.z;
            if (iw * Sb > iwb * S) { iwb = iw; Sb = S; bx1 = c0.x; blen = c0.z; }
        }
        {
            const float iw = fmaxf(fminf(a1, c1.y) - fmaxf(a0, c1.x), 0.0f);
            const float S  = aw + c1.z;
            if (iw * Sb > iwb * S) { iwb = iw; Sb = S; bx1 = c1.x; blen = c1.z; }
        }
        {
            const float iw = fmaxf(fminf(a1, c2.y) - fmaxf(a0, c2.x), 0.0f);
            const float S  = aw + c2.z;
            if (iw * Sb > iwb * S) { iwb = iw; Sb = S; bx1 = c2.x; blen = c2.z; }
        }
        unsigned long long mrest =
            ((unsigned long long)__float_as_uint(r0.y) << 32) |
            (unsigned long long)__float_as_uint(r0.x);
        while (mrest) {                  // rare: bins with >3 candidates
            const int m = __ffsll(mrest) - 1;
            mrest &= mrest - 1;
            const float4 g = annb[m];
            const float iw = fmaxf(fminf(a1, g.y) - fmaxf(a0, g.x), 0.0f);
            const float S  = aw + g.z;
            if (iw * Sb > iwb * S) { iwb = iw; Sb = S; bx1 = g.x; blen = g.z; }
        }

        // exact gate, reference rounding order: ua = (aw+len) - iw
        const float ua  = fmaxf(Sb - iwb, 1e-8f);
        const float iou = iwb / ua;
        if (pact && iou >= 0.5f) {
            const float gcx = bx1 + 0.5f * blen;
            const float gw  = fmaxf(blen, 1.0f);
            const float acx = a0 + 0.5f * aw;
            const float tdx = ((gcx - acx) / aw) / 0.1f;
            const float tdw = logf(gw / aw) / 0.2f;
            const float2 rg =
                ((const float2*)regressions)[(size_t)b * A_N + a_idx];
            const float d0 = fabsf(tdx - rg.x);
            const float d1 = fabsf(tdw - rg.y);
            const float inv9 = 1.0f / 9.0f;
            const float s0 = (d0 <= inv9) ? 4.5f * d0 * d0 : d0 - 0.5f / 9.0f;
            const float s1 = (d1 <= inv9) ? 4.5f * d1 * d1 : d1 - 0.5f / 9.0f;
            lsum += s0 + s1;
            lpos += 1.0f;
        }
    }

    for (int o = 32; o > 0; o >>= 1) {
        lsum += __shfl_down(lsum, o, 64);
        lpos += __shfl_down(lpos, o, 64);
    }
    __shared__ float wsum[TPB / 64], wpos[TPB / 64];
    const int wid  = tid >> 6;
    const int lane = tid & 63;
    if (lane == 0) { wsum[wid] = lsum; wpos[wid] = lpos; }
    __syncthreads();
    if (tid == 0) {
        float s = 0.0f, p = 0.0f;
        #pragma unroll
        for (int w = 0; w < TPB / 64; ++w) { s += wsum[w]; p += wpos[w]; }
        const int slot = b * GX + blockIdx.x;
        ws_num[slot] = s;
        ws_cnt[slot] = p;
    }
}

__global__ __launch_bounds__(512) void rl_final(
    const float* __restrict__ ws_num,
    const float* __restrict__ ws_cnt,
    float* __restrict__ out)
{
    const int wid  = threadIdx.x >> 6;   // wave w handles batch w
    const int lane = threadIdx.x & 63;
    float s = 0.0f, c = 0.0f;
    for (int i = lane; i < GX; i += 64) {
        s += ws_num[wid * GX + i];
        c += ws_cnt[wid * GX + i];
    }
    for (int o = 32; o > 0; o >>= 1) {
        s += __shfl_down(s, o, 64);
        c += __shfl_down(c, o, 64);
    }
    __shared__ float pb[B_N];
    if (lane == 0) {
        const float cnt = 2.0f * c;
        pb[wid] = (cnt > 0.0f) ? s / fmaxf(cnt, 1.0f) : 0.0f;
    }
    __syncthreads();
    if (threadIdx.x == 0) {
        float acc = 0.0f;
        #pragma unroll
        for (int i = 0; i < B_N; ++i) acc += pb[i];
        out[0] = acc * (1.0f / (float)B_N);
    }
}

extern "C" void kernel_launch(void* const* d_in, const int* in_sizes, int n_in,
                              void* d_out, int out_size, void* d_ws, size_t ws_size,
                              hipStream_t stream) {
    const float* regressions = (const float*)d_in[0];
    const float* anchors     = (const float*)d_in[1];
    const float* annotations = (const float*)d_in[2];
    float* out = (float*)d_out;

    float4* recs   = (float4*)d_ws;                      // [B_N*NBINS*4]
    float4* ann_t  = recs + (size_t)B_N * NBINS * 4;     // [B_N*M_N]
    float*  ws_num = (float*)(ann_t + B_N * M_N);        // [B_N*GX]
    float*  ws_cnt = ws_num + B_N * GX;                  // [B_N*GX]

    rl_prep<<<B_N, TPB, 0, stream>>>(annotations, recs, ann_t);
    rl_main<<<dim3(GX, B_N), TPB, 0, stream>>>(regressions, anchors, recs,
                                               ann_t, ws_num, ws_cnt);
    rl_final<<<1, 512, 0, stream>>>(ws_num, ws_cnt, out);
}

// Round 13
// 74.620 us; speedup vs baseline: 1.5128x; 1.0784x over previous
//
#include <hip/hip_runtime.h>

#define B_N 8
#define A_N 100000
#define M_N 64
#define TPB 256
#define PAIRS (A_N / 2)                               // 50000, A_N even
#define GX ((PAIRS + TPB - 1) / TPB)                  // 196 blocks per batch

#define NBINS 256
#define BINW  12.0f         // covers a0 in [0, 3072); a0 <= 3000
#define MAXAW 50.0f
#define MARG  1.0f

// d_ws: ws_num[B_N*GX], ws_cnt[B_N*GX] only. Each slot written every call
// before rl_final reads it (poison-proof). No prep kernel: every block
// rebuilds the 2KB bin table + 1KB ann cache in LDS (~600 lane-cycles).

__global__ __launch_bounds__(TPB) void rl_main(
    const float* __restrict__ regressions,   // (B, A, 2)
    const float* __restrict__ anchors,       // (1, A, 2)
    const float* __restrict__ annotations,   // (B, M, 3)
    float* __restrict__ ws_num, float* __restrict__ ws_cnt)
{
    __shared__ unsigned long long tbl[NBINS];   // 2 KB: bin -> candidate mask
    __shared__ float4 annl[M_N];                // 1 KB: {x1, x2, len, 0}
    const int b = blockIdx.y;
    const int tid = threadIdx.x;

    // ---- in-block prep: thread t owns bin t (wave-uniform scalar loads) ----
    {
        const float* p = annotations + b * M_N * 3;
        const float binlo = tid * BINW;
        const float binhi = binlo + BINW;
        unsigned long long mask = 0ull;
        #pragma unroll 8
        for (int m = 0; m < M_N; ++m) {
            const float x1 = p[3 * m + 0], x2 = p[3 * m + 1], lab = p[3 * m + 2];
            if (lab != -1.0f) {
                // iou>=0.5 => overlap >= len/3 => a0 in [x1+len/3-aw, x2-len/3],
                // aw<=50. Margin 1.0 >> fp32 rounding at coords <= ~3e3.
                const float len3 = (x2 - x1) * (1.0f / 3.0f);
                const float lo = x1 + len3 - MAXAW - MARG;
                const float hi = x2 - len3 + MARG;
                if (binlo <= hi && binhi > lo) mask |= (1ull << m);
            }
        }
        tbl[tid] = mask;
        if (tid < M_N) {
            float x1 = p[3 * tid + 0], x2 = p[3 * tid + 1], lab = p[3 * tid + 2];
            if (lab == -1.0f) { x1 = 1e30f; x2 = 1e30f; }   // never in masks
            annl[tid] = make_float4(x1, x2, x2 - x1, 0.0f);
        }
    }
    __syncthreads();

    // ---- hot phase: one float4 = two adjacent anchors per thread ----
    const int pair_raw = blockIdx.x * TPB + tid;
    const bool pact = (pair_raw < PAIRS);
    const int pair = pact ? pair_raw : (PAIRS - 1);
    const float4 anc2 = ((const float4*)anchors)[pair];

    float lsum = 0.0f, lpos = 0.0f;
    #pragma unroll
    for (int k = 0; k < 2; ++k) {
        const float a0 = k ? anc2.z : anc2.x;
        const float a1 = k ? anc2.w : anc2.y;
        const float aw = a1 - a0;
        const int a_idx = 2 * pair + k;

        const int bin = min(max((int)(a0 * (1.0f / BINW)), 0), NBINS - 1);
        unsigned long long mask = tbl[bin];

        // exact argmax over the candidate superset, ascending index,
        // strict '>' (division-free cross-mul on iou = iw/(S-iw), S=aw+len)
        float iwb = -1.0f, Sb = 1.0f;    // encodes iou = -1
        float bx1 = 1e30f, blen = 0.0f;  // winner carries its values
        while (mask) {
            const int m = __ffsll(mask) - 1;
            mask &= mask - 1;
            const float4 g = annl[m];
            const float iw = fmaxf(fminf(a1, g.y) - fmaxf(a0, g.x), 0.0f);
            const float S  = aw + g.z;
            if (iw * Sb > iwb * S) { iwb = iw; Sb = S; bx1 = g.x; blen = g.z; }
        }

        // exact gate, reference rounding order: ua = (aw+len) - iw
        const float ua  = fmaxf(Sb - iwb, 1e-8f);
        const float iou = iwb / ua;
        if (pact && iou >= 0.5f) {
            const float gcx = bx1 + 0.5f * blen;
            const float gw  = fmaxf(blen, 1.0f);
            const float acx = a0 + 0.5f * aw;
            const float tdx = ((gcx - acx) / aw) / 0.1f;
            const float tdw = logf(gw / aw) / 0.2f;
            const float2 rg =
                ((const float2*)regressions)[(size_t)b * A_N + a_idx];
            const float d0 = fabsf(tdx - rg.x);
            const float d1 = fabsf(tdw - rg.y);
            const float inv9 = 1.0f / 9.0f;
            const float s0 = (d0 <= inv9) ? 4.5f * d0 * d0 : d0 - 0.5f / 9.0f;
            const float s1 = (d1 <= inv9) ? 4.5f * d1 * d1 : d1 - 0.5f / 9.0f;
            lsum += s0 + s1;
            lpos += 1.0f;
        }
    }

    for (int o = 32; o > 0; o >>= 1) {
        lsum += __shfl_down(lsum, o, 64);
        lpos += __shfl_down(lpos, o, 64);
    }
    __shared__ float wsum[TPB / 64], wpos[TPB / 64];
    const int wid  = tid >> 6;
    const int lane = tid & 63;
    if (lane == 0) { wsum[wid] = lsum; wpos[wid] = lpos; }
    __syncthreads();
    if (tid == 0) {
        float s = 0.0f, p = 0.0f;
        #pragma unroll
        for (int w = 0; w < TPB / 64; ++w) { s += wsum[w]; p += wpos[w]; }
        const int slot = b * GX + blockIdx.x;
        ws_num[slot] = s;
        ws_cnt[slot] = p;
    }
}

__global__ __launch_bounds__(512) void rl_final(
    const float* __restrict__ ws_num,
    const float* __restrict__ ws_cnt,
    float* __restrict__ out)
{
    const int wid  = threadIdx.x >> 6;   // wave w handles batch w
    const int lane = threadIdx.x & 63;
    float s = 0.0f, c = 0.0f;
    for (int i = lane; i < GX; i += 64) {
        s += ws_num[wid * GX + i];
        c += ws_cnt[wid * GX + i];
    }
    for (int o = 32; o > 0; o >>= 1) {
        s += __shfl_down(s, o, 64);
        c += __shfl_down(c, o, 64);
    }
    __shared__ float pb[B_N];
    if (lane == 0) {
        const float cnt = 2.0f * c;
        pb[wid] = (cnt > 0.0f) ? s / fmaxf(cnt, 1.0f) : 0.0f;
    }
    __syncthreads();
    if (threadIdx.x == 0) {
        float acc = 0.0f;
        #pragma unroll
        for (int i = 0; i < B_N; ++i) acc += pb[i];
        out[0] = acc * (1.0f / (float)B_N);
    }
}

extern "C" void kernel_launch(void* const* d_in, const int* in_sizes, int n_in,
                              void* d_out, int out_size, void* d_ws, size_t ws_size,
                              hipStream_t stream) {
    const float* regressions = (const float*)d_in[0];
    const float* anchors     = (const float*)d_in[1];
    const float* annotations = (const float*)d_in[2];
    float* out = (float*)d_out;

    float* ws_num = (float*)d_ws;                 // [B_N * GX]
    float* ws_cnt = ws_num + B_N * GX;            // [B_N * GX]

    rl_main<<<dim3(GX, B_N), TPB, 0, stream>>>(regressions, anchors,
                                               annotations, ws_num, ws_cnt);
    rl_final<<<1, 512, 0, stream>>>(ws_num, ws_cnt, out);
}

// Round 14
// 66.505 us; speedup vs baseline: 1.6974x; 1.1220x over previous
//
#include <hip/hip_runtime.h>

#define B_N 8
#define A_N 100000
#define M_N 64
#define TPB 256
#define PAIRS (A_N / 2)                               // 50000, A_N even
#define GX ((PAIRS + TPB - 1) / TPB)                  // 196 blocks per batch

#define NBINS 256
#define BINW  12.0f         // covers a0 in [0, 3072); a0 <= 3000
#define MAXAW 50.0f
#define MARG  1.0f

// d_ws: ws_num[B_N*GX], ws_cnt[B_N*GX]. Each slot written every call before
// rl_final reads it (poison-proof). No prep kernel: blocks build the 2KB bin
// table ann-side (~6 LDS atomicOr per ann on one wave) + 1KB ann cache.

__global__ __launch_bounds__(TPB) void rl_main(
    const float* __restrict__ regressions,   // (B, A, 2)
    const float* __restrict__ anchors,       // (1, A, 2)
    const float* __restrict__ annotations,   // (B, M, 3)
    float* __restrict__ ws_num, float* __restrict__ ws_cnt)
{
    __shared__ unsigned int tblLo[NBINS];       // bits 0..31  (anns 0-31)
    __shared__ unsigned int tblHi[NBINS];       // bits 32..63 (anns 32-63)
    __shared__ float4 annl[M_N];                // {x1, x2, len, 0}
    const int b = blockIdx.y;
    const int tid = threadIdx.x;

    // ---- in-block prep, ann-side scatter ----
    tblLo[tid] = 0u;
    tblHi[tid] = 0u;
    __syncthreads();
    if (tid < M_N) {
        const float* p = annotations + (b * M_N + tid) * 3;
        float x1 = p[0], x2 = p[1];
        const float lab = p[2];
        const bool valid = (lab != -1.0f);
        if (!valid) { x1 = 1e30f; x2 = 1e30f; }   // never enters the table
        annl[tid] = make_float4(x1, x2, x2 - x1, 0.0f);
        if (valid) {
            // iou>=0.5 => overlap >= len/3 => a0 in [x1+len/3-aw, x2-len/3],
            // aw<=50. Margin 1.0 >> fp32 rounding at coords <= ~3e3.
            // bin b intersects [lo,hi] iff b*W <= hi && (b+1)*W > lo
            //   <=> b in [floor(lo/W), floor(hi/W)] (exact at multiples of W).
            const float len3 = (x2 - x1) * (1.0f / 3.0f);
            const float lo = x1 + len3 - MAXAW - MARG;
            const float hi = x2 - len3 + MARG;
            const int blo = max(0, (int)floorf(lo * (1.0f / BINW)));
            const int bhi = min(NBINS - 1, (int)floorf(hi * (1.0f / BINW)));
            const unsigned int bit = 1u << (tid & 31);
            unsigned int* dst = (tid < 32) ? tblLo : tblHi;
            for (int bb = blo; bb <= bhi; ++bb) atomicOr(&dst[bb], bit);
        }
    }
    __syncthreads();

    // ---- hot phase: one float4 = two adjacent anchors per thread ----
    const int pair_raw = blockIdx.x * TPB + tid;
    const bool pact = (pair_raw < PAIRS);
    const int pair = pact ? pair_raw : (PAIRS - 1);
    const float4 anc2 = ((const float4*)anchors)[pair];

    float lsum = 0.0f, lpos = 0.0f;
    #pragma unroll
    for (int k = 0; k < 2; ++k) {
        const float a0 = k ? anc2.z : anc2.x;
        const float a1 = k ? anc2.w : anc2.y;
        const float aw = a1 - a0;
        const int a_idx = 2 * pair + k;

        const int bin = min(max((int)(a0 * (1.0f / BINW)), 0), NBINS - 1);
        unsigned long long mask =
            ((unsigned long long)tblHi[bin] << 32) |
            (unsigned long long)tblLo[bin];

        // exact argmax over the candidate superset, ascending index,
        // strict '>' (division-free cross-mul on iou = iw/(S-iw), S=aw+len)
        float iwb = -1.0f, Sb = 1.0f;    // encodes iou = -1
        float bx1 = 1e30f, blen = 0.0f;  // winner carries its values
        while (mask) {
            const int m = __ffsll(mask) - 1;
            mask &= mask - 1;
            const float4 g = annl[m];
            const float iw = fmaxf(fminf(a1, g.y) - fmaxf(a0, g.x), 0.0f);
            const float S  = aw + g.z;
            if (iw * Sb > iwb * S) { iwb = iw; Sb = S; bx1 = g.x; blen = g.z; }
        }

        // exact gate, reference rounding order: ua = (aw+len) - iw
        const float ua  = fmaxf(Sb - iwb, 1e-8f);
        const float iou = iwb / ua;
        if (pact && iou >= 0.5f) {
            const float gcx = bx1 + 0.5f * blen;
            const float gw  = fmaxf(blen, 1.0f);
            const float acx = a0 + 0.5f * aw;
            const float tdx = ((gcx - acx) / aw) / 0.1f;
            const float tdw = logf(gw / aw) / 0.2f;
            const float2 rg =
                ((const float2*)regressions)[(size_t)b * A_N + a_idx];
            const float d0 = fabsf(tdx - rg.x);
            const float d1 = fabsf(tdw - rg.y);
            const float inv9 = 1.0f / 9.0f;
            const float s0 = (d0 <= inv9) ? 4.5f * d0 * d0 : d0 - 0.5f / 9.0f;
            const float s1 = (d1 <= inv9) ? 4.5f * d1 * d1 : d1 - 0.5f / 9.0f;
            lsum += s0 + s1;
            lpos += 1.0f;
        }
    }

    for (int o = 32; o > 0; o >>= 1) {
        lsum += __shfl_down(lsum, o, 64);
        lpos += __shfl_down(lpos, o, 64);
    }
    __shared__ float wsum[TPB / 64], wpos[TPB / 64];
    const int wid  = tid >> 6;
    const int lane = tid & 63;
    if (lane == 0) { wsum[wid] = lsum; wpos[wid] = lpos; }
    __syncthreads();
    if (tid == 0) {
        float s = 0.0f, p = 0.0f;
        #pragma unroll
        for (int w = 0; w < TPB / 64; ++w) { s += wsum[w]; p += wpos[w]; }
        const int slot = b * GX + blockIdx.x;
        ws_num[slot] = s;
        ws_cnt[slot] = p;
    }
}

__global__ __launch_bounds__(512) void rl_final(
    const float* __restrict__ ws_num,
    const float* __restrict__ ws_cnt,
    float* __restrict__ out)
{
    const int wid  = threadIdx.x >> 6;   // wave w handles batch w
    const int lane = threadIdx.x & 63;
    float s = 0.0f, c = 0.0f;
    for (int i = lane; i < GX; i += 64) {
        s += ws_num[wid * GX + i];
        c += ws_cnt[wid * GX + i];
    }
    for (int o = 32; o > 0; o >>= 1) {
        s += __shfl_down(s, o, 64);
        c += __shfl_down(c, o, 64);
    }
    __shared__ float pb[B_N];
    if (lane == 0) {
        const float cnt = 2.0f * c;
        pb[wid] = (cnt > 0.0f) ? s / fmaxf(cnt, 1.0f) : 0.0f;
    }
    __syncthreads();
    if (threadIdx.x == 0) {
        float acc = 0.0f;
        #pragma unroll
        for (int i = 0; i < B_N; ++i) acc += pb[i];
        out[0] = acc * (1.0f / (float)B_N);
    }
}

extern "C" void kernel_launch(void* const* d_in, const int* in_sizes, int n_in,
                              void* d_out, int out_size, void* d_ws, size_t ws_size,
                              hipStream_t stream) {
    const float* regressions = (const float*)d_in[0];
    const float* anchors     = (const float*)d_in[1];
    const float* annotations = (const float*)d_in[2];
    float* out = (float*)d_out;

    float* ws_num = (float*)d_ws;                 // [B_N * GX]
    float* ws_cnt = ws_num + B_N * GX;            // [B_N * GX]

    rl_main<<<dim3(GX, B_N), TPB, 0, stream>>>(regressions, anchors,
                                               annotations, ws_num, ws_cnt);
    rl_final<<<1, 512, 0, stream>>>(ws_num, ws_cnt, out);
}